// Round 1
// baseline (583.743 us; speedup 1.0000x reference)
//
#include <hip/hip_runtime.h>

#define L_AUDIO 15360000
#define PADLEN  15361024   // L + 1024
#define FRAMES  30001
#define CHP     513        // channel pairs (real k, imag k+513)
#define NBAS    (1026*1024)

typedef __attribute__((ext_vector_type(8))) short short8;
typedef __attribute__((ext_vector_type(4))) float f32x4;

__device__ __forceinline__ unsigned short f2bf(float f) {
    unsigned int u = __float_as_uint(f);
    u += 0x7fffu + ((u >> 16) & 1u);   // round-to-nearest-even
    return (unsigned short)(u >> 16);
}

// Build reflect-padded bf16 audio: pad[p] = bf16(audio[reflect(p)])
__global__ __launch_bounds__(256) void prep_pad_k(const float* __restrict__ a,
                                                  unsigned short* __restrict__ pad) {
    long i = (long)blockIdx.x * blockDim.x + threadIdx.x;   // [0, PADLEN/4)
    long p0 = i * 4;
    if (p0 >= 512 && p0 + 4 <= 512 + L_AUDIO) {
        const float4 v = *reinterpret_cast<const float4*>(a + (p0 - 512));
        ushort4 o;
        o.x = f2bf(v.x); o.y = f2bf(v.y); o.z = f2bf(v.z); o.w = f2bf(v.w);
        *reinterpret_cast<ushort4*>(pad + p0) = o;
    } else {
        for (int j = 0; j < 4; ++j) {
            long p = p0 + j;
            long src = p - 512;
            if (p < 512) src = 512 - p;                       // left reflect
            else if (src >= L_AUDIO) src = 2L*L_AUDIO - 2 - src; // right reflect
            pad[p] = f2bf(a[src]);
        }
    }
}

// Convert basis fp32 -> bf16 (row-major [1026][1024])
__global__ __launch_bounds__(256) void prep_bas_k(const float* __restrict__ b,
                                                  unsigned short* __restrict__ o) {
    long i = (long)blockIdx.x * blockDim.x + threadIdx.x;    // [0, NBAS/4)
    const float4 v = *reinterpret_cast<const float4*>(b + i * 4);
    ushort4 u;
    u.x = f2bf(v.x); u.y = f2bf(v.y); u.z = f2bf(v.z); u.w = f2bf(v.w);
    *reinterpret_cast<ushort4*>(o + i * 4) = u;
}

// GEMM: block tile = 32 frames (M) x 64 channel-pairs (N), 4 waves (2M x 2N).
// Per wave: M=16 frames, N=32 pairs => 2 n-tiles x {real,imag} = 4 accumulators.
__global__ __launch_bounds__(256) void stft_gemm(const unsigned short* __restrict__ pad,
                                                 const unsigned short* __restrict__ bas,
                                                 float* __restrict__ out) {
    const int tid  = threadIdx.x;
    const int wid  = tid >> 6;
    const int lane = tid & 63;
    const int wm = wid >> 1;          // 0..1  (frame half)
    const int wn = wid & 1;           // 0..1  (channel half)
    const int l15 = lane & 15;
    const int lk  = lane >> 4;        // k-group 0..3

    const long t0  = (long)blockIdx.x * 32;
    const int  ch0 = blockIdx.y * 64 + wn * 32;

    // A fragment source: frame rows (clamped), contiguous K
    int tA = (int)t0 + wm * 16 + l15;
    if (tA > FRAMES - 1) tA = FRAMES - 1;
    const unsigned short* aptr = pad + (long)tA * 512 + lk * 8;

    // B fragment sources: basis rows (clamped to pair 512), contiguous K
    const int chA = ch0 + l15;        // n-tile 0
    const int chB = ch0 + 16 + l15;   // n-tile 1
    const int chA_l = chA > 512 ? 512 : chA;
    const int chB_l = chB > 512 ? 512 : chB;
    const unsigned short* br0 = bas + (long)chA_l * 1024 + lk * 8;
    const unsigned short* br1 = bas + (long)chB_l * 1024 + lk * 8;
    const unsigned short* bi0 = br0 + (long)513 * 1024;
    const unsigned short* bi1 = br1 + (long)513 * 1024;

    f32x4 ar0 = {0.f,0.f,0.f,0.f}, ar1 = {0.f,0.f,0.f,0.f};
    f32x4 ai0 = {0.f,0.f,0.f,0.f}, ai1 = {0.f,0.f,0.f,0.f};

    #pragma unroll 4
    for (int kk = 0; kk < 1024; kk += 32) {
        short8 a  = *reinterpret_cast<const short8*>(aptr);
        short8 v0 = *reinterpret_cast<const short8*>(br0);
        short8 v1 = *reinterpret_cast<const short8*>(br1);
        short8 w0 = *reinterpret_cast<const short8*>(bi0);
        short8 w1 = *reinterpret_cast<const short8*>(bi1);
        ar0 = __builtin_amdgcn_mfma_f32_16x16x32_bf16(a, v0, ar0, 0, 0, 0);
        ar1 = __builtin_amdgcn_mfma_f32_16x16x32_bf16(a, v1, ar1, 0, 0, 0);
        ai0 = __builtin_amdgcn_mfma_f32_16x16x32_bf16(a, w0, ai0, 0, 0, 0);
        ai1 = __builtin_amdgcn_mfma_f32_16x16x32_bf16(a, w1, ai1, 0, 0, 0);
        aptr += 32; br0 += 32; br1 += 32; bi0 += 32; bi1 += 32;
    }

    // Epilogue: out[ch][t] = real^2 + imag^2
    // D mapping (m89-verified): col = lane&15 (channel), row = (lane>>4)*4 + reg (frame)
    const int trow = (int)t0 + wm * 16 + lk * 4;
    #pragma unroll
    for (int r = 0; r < 4; ++r) {
        const int t = trow + r;
        if (t <= FRAMES - 1) {
            if (chA < CHP)
                out[(long)chA * FRAMES + t] = ar0[r]*ar0[r] + ai0[r]*ai0[r];
            if (chB < CHP)
                out[(long)chB * FRAMES + t] = ar1[r]*ar1[r] + ai1[r]*ai1[r];
        }
    }
}

extern "C" void kernel_launch(void* const* d_in, const int* in_sizes, int n_in,
                              void* d_out, int out_size, void* d_ws, size_t ws_size,
                              hipStream_t stream) {
    const float* audio = (const float*)d_in[0];
    const float* basis = (const float*)d_in[1];
    float* out = (float*)d_out;

    unsigned short* pad = (unsigned short*)d_ws;            // PADLEN bf16 = 30.7 MB
    unsigned short* bas = pad + PADLEN;                     // NBAS bf16   =  2.1 MB

    prep_pad_k<<<PADLEN / 4 / 256, 256, 0, stream>>>(audio, pad);
    prep_bas_k<<<NBAS / 4 / 256, 256, 0, stream>>>(basis, bas);

    dim3 grid((FRAMES + 31) / 32, (CHP + 63) / 64);         // 938 x 9
    stft_gemm<<<grid, 256, 0, stream>>>(pad, bas, out);
}

// Round 2
// 132.195 us; speedup vs baseline: 4.4158x; 4.4158x over previous
//
#include <hip/hip_runtime.h>

#define L_AUDIO 15360000
#define PADLEN  15361024   // L + 1024
#define FRAMES  30001
#define CHP     513        // channel pairs (real k, imag k+513)
#define NBAS    (1026*1024)

#define BM  128            // frames per block
#define BNP 64             // channel pairs per block (=> 128 basis rows)
#define BK  64

typedef __attribute__((ext_vector_type(8))) short short8;
typedef __attribute__((ext_vector_type(4))) float f32x4;

__device__ __forceinline__ unsigned short f2bf(float f) {
    unsigned int u = __float_as_uint(f);
    u += 0x7fffu + ((u >> 16) & 1u);   // round-to-nearest-even
    return (unsigned short)(u >> 16);
}

__global__ __launch_bounds__(256) void prep_pad_k(const float* __restrict__ a,
                                                  unsigned short* __restrict__ pad) {
    long i = (long)blockIdx.x * blockDim.x + threadIdx.x;   // [0, PADLEN/4)
    long p0 = i * 4;
    if (p0 >= 512 && p0 + 4 <= 512 + L_AUDIO) {
        const float4 v = *reinterpret_cast<const float4*>(a + (p0 - 512));
        ushort4 o;
        o.x = f2bf(v.x); o.y = f2bf(v.y); o.z = f2bf(v.z); o.w = f2bf(v.w);
        *reinterpret_cast<ushort4*>(pad + p0) = o;
    } else {
        for (int j = 0; j < 4; ++j) {
            long p = p0 + j;
            long src = p - 512;
            if (p < 512) src = 512 - p;
            else if (src >= L_AUDIO) src = 2L*L_AUDIO - 2 - src;
            pad[p] = f2bf(a[src]);
        }
    }
}

__global__ __launch_bounds__(256) void prep_bas_k(const float* __restrict__ b,
                                                  unsigned short* __restrict__ o) {
    long i = (long)blockIdx.x * blockDim.x + threadIdx.x;
    const float4 v = *reinterpret_cast<const float4*>(b + i * 4);
    ushort4 u;
    u.x = f2bf(v.x); u.y = f2bf(v.y); u.z = f2bf(v.z); u.w = f2bf(v.w);
    *reinterpret_cast<ushort4*>(o + i * 4) = u;
}

// LDS tiles are [128 rows][64 bf16] = 128B rows, XOR-swizzled:
// data for logical 16B-chunk c of row r sits at physical chunk c^(r&7).
// global_load_lds writes linearly, so the SOURCE address is pre-swizzled
// (rule 21) and reads apply the same XOR.
__global__ __launch_bounds__(256) void stft_gemm(const unsigned short* __restrict__ pad,
                                                 const unsigned short* __restrict__ bas,
                                                 float* __restrict__ out) {
    __shared__ unsigned short lsA[BM * BK];   // 16 KB
    __shared__ unsigned short lsB[BM * BK];   // 16 KB

    const int tid  = threadIdx.x;
    const int w    = tid >> 6;
    const int lane = tid & 63;
    const int l15  = lane & 15;
    const int lk   = lane >> 4;

    const int  c0 = blockIdx.x * BNP;         // pair-block (fast dim -> audio L2/L3 reuse)
    const long t0 = (long)blockIdx.y * BM;    // frame-block

    // Per-lane staging sources: 4 wave-loads each for A and B (16 loads/tile total).
    const unsigned short* asrc[4];
    const unsigned short* bsrc[4];
    int ldsbase[4];
    #pragma unroll
    for (int j = 0; j < 4; ++j) {
        const int i = w * 4 + j;              // wave-load index 0..15
        const int c = i * 64 + lane;          // 16B-chunk index 0..1023
        const int row = c >> 3;               // 0..127
        const int chlog = (c & 7) ^ (row & 7);// pre-swizzled source chunk
        ldsbase[j] = i * 512;                 // ushort index of 1KB wave-load chunk
        // A: frame row
        long t = t0 + row; if (t > FRAMES - 1) t = FRAMES - 1;
        asrc[j] = pad + t * 512 + chlog * 8;
        // B: basis row (0..63 real pairs, 64..127 imag pairs)
        int ch = c0 + (row & 63); if (ch > 512) ch = 512;
        long brow = (row < 64) ? (long)ch : (long)(513 + ch);
        bsrc[j] = bas + brow * 1024 + chlog * 8;
    }

    f32x4 acc[2][8];
    #pragma unroll
    for (int m = 0; m < 2; ++m)
        #pragma unroll
        for (int n = 0; n < 8; ++n)
            acc[m][n] = (f32x4){0.f, 0.f, 0.f, 0.f};

    for (int kk = 0; kk < 1024; kk += BK) {
        if (kk) __syncthreads();              // previous compute done before overwrite
        #pragma unroll
        for (int j = 0; j < 4; ++j) {
            __builtin_amdgcn_global_load_lds(
                (const __attribute__((address_space(1))) unsigned int*)(asrc[j] + kk),
                (__attribute__((address_space(3))) unsigned int*)&lsA[ldsbase[j]],
                16, 0, 0);
            __builtin_amdgcn_global_load_lds(
                (const __attribute__((address_space(1))) unsigned int*)(bsrc[j] + kk),
                (__attribute__((address_space(3))) unsigned int*)&lsB[ldsbase[j]],
                16, 0, 0);
        }
        __syncthreads();                      // compiler drains vmcnt(0) here

        #pragma unroll
        for (int s = 0; s < 2; ++s) {
            short8 af[2], bf[8];
            #pragma unroll
            for (int m = 0; m < 2; ++m) {
                const int r = w * 32 + m * 16 + l15;
                const int byt = (s * 64 + lk * 16) ^ ((r & 7) << 4);
                af[m] = *reinterpret_cast<const short8*>(
                    reinterpret_cast<const char*>(lsA) + r * 128 + byt);
            }
            #pragma unroll
            for (int n = 0; n < 8; ++n) {
                const int r = n * 16 + l15;
                const int byt = (s * 64 + lk * 16) ^ ((r & 7) << 4);
                bf[n] = *reinterpret_cast<const short8*>(
                    reinterpret_cast<const char*>(lsB) + r * 128 + byt);
            }
            #pragma unroll
            for (int m = 0; m < 2; ++m)
                #pragma unroll
                for (int n = 0; n < 8; ++n)
                    acc[m][n] = __builtin_amdgcn_mfma_f32_16x16x32_bf16(af[m], bf[n], acc[m][n], 0, 0, 0);
        }
    }

    // Epilogue: out[ch][t] = re^2 + im^2
    // D layout: col = lane&15 (basis row / channel), row = lk*4 + reg (frame)
    const int tbase = (int)t0 + w * 32;
    #pragma unroll
    for (int m = 0; m < 2; ++m) {
        #pragma unroll
        for (int n = 0; n < 4; ++n) {
            const int ch = c0 + n * 16 + l15;
            if (ch >= CHP) continue;
            const long obase = (long)ch * FRAMES;
            #pragma unroll
            for (int r = 0; r < 4; ++r) {
                const int t = tbase + m * 16 + lk * 4 + r;
                if (t < FRAMES) {
                    const float re = acc[m][n][r], im = acc[m][n + 4][r];
                    out[obase + t] = re * re + im * im;
                }
            }
        }
    }
}

extern "C" void kernel_launch(void* const* d_in, const int* in_sizes, int n_in,
                              void* d_out, int out_size, void* d_ws, size_t ws_size,
                              hipStream_t stream) {
    const float* audio = (const float*)d_in[0];
    const float* basis = (const float*)d_in[1];
    float* out = (float*)d_out;

    unsigned short* pad = (unsigned short*)d_ws;
    unsigned short* bas = pad + PADLEN;

    prep_pad_k<<<PADLEN / 4 / 256, 256, 0, stream>>>(audio, pad);
    prep_bas_k<<<NBAS / 4 / 256, 256, 0, stream>>>(basis, bas);

    dim3 grid((CHP + BNP - 1) / BNP, (FRAMES + BM - 1) / BM);   // 9 x 235
    stft_gemm<<<grid, 256, 0, stream>>>(pad, bas, out);
}

// Round 3
// 126.547 us; speedup vs baseline: 4.6129x; 1.0446x over previous
//
#include <hip/hip_runtime.h>

#define L_AUDIO 15360000
#define PADLEN  15361024   // L + 1024
#define FRAMES  30001
#define CHP     513        // channel pairs (real k, imag k+513)
#define NBAS    (1026*1024)

#define BM  128            // frames per block
#define BNP 64             // channel pairs per block (=> 128 basis rows)
#define BK  64
#define NKT 16             // 1024 / BK
#define NCB 9              // channel blocks
#define NFB 235            // frame blocks

typedef __attribute__((ext_vector_type(8))) short short8;
typedef __attribute__((ext_vector_type(4))) float f32x4;

__device__ __forceinline__ unsigned short f2bf(float f) {
    unsigned int u = __float_as_uint(f);
    u += 0x7fffu + ((u >> 16) & 1u);   // round-to-nearest-even
    return (unsigned short)(u >> 16);
}

__global__ __launch_bounds__(256) void prep_pad_k(const float* __restrict__ a,
                                                  unsigned short* __restrict__ pad) {
    long i = (long)blockIdx.x * blockDim.x + threadIdx.x;   // [0, PADLEN/4)
    long p0 = i * 4;
    if (p0 >= 512 && p0 + 4 <= 512 + L_AUDIO) {
        const float4 v = *reinterpret_cast<const float4*>(a + (p0 - 512));
        ushort4 o;
        o.x = f2bf(v.x); o.y = f2bf(v.y); o.z = f2bf(v.z); o.w = f2bf(v.w);
        *reinterpret_cast<ushort4*>(pad + p0) = o;
    } else {
        for (int j = 0; j < 4; ++j) {
            long p = p0 + j;
            long src = p - 512;
            if (p < 512) src = 512 - p;
            else if (src >= L_AUDIO) src = 2L*L_AUDIO - 2 - src;
            pad[p] = f2bf(a[src]);
        }
    }
}

__global__ __launch_bounds__(256) void prep_bas_k(const float* __restrict__ b,
                                                  unsigned short* __restrict__ o) {
    long i = (long)blockIdx.x * blockDim.x + threadIdx.x;
    const float4 v = *reinterpret_cast<const float4*>(b + i * 4);
    ushort4 u;
    u.x = f2bf(v.x); u.y = f2bf(v.y); u.z = f2bf(v.z); u.w = f2bf(v.w);
    *reinterpret_cast<ushort4*>(o + i * 4) = u;
}

// Double-buffered LDS (64 KB), XOR-swizzled rows (rule 21: linear gload_lds
// dest + pre-swizzled global source + swizzled ds_read).
// XCD-chunked grid (T1/m204): xcd = bid&7 owns contiguous frame-blocks,
// channel-fast within, so the 9 channel-blocks sharing a frame tile hit the
// same per-XCD L2.
__global__ __launch_bounds__(256) void stft_gemm(const unsigned short* __restrict__ pad,
                                                 const unsigned short* __restrict__ bas,
                                                 float* __restrict__ out) {
    __shared__ unsigned short lsA[2][BM * BK];   // 2 x 16 KB
    __shared__ unsigned short lsB[2][BM * BK];   // 2 x 16 KB

    const int bid = blockIdx.x;
    const int xcd = bid & 7;
    const int idx = bid >> 3;                    // 0..269
    const int nfb = (xcd < 3) ? 30 : 29;         // 235 = 3*30 + 5*29
    if (idx >= nfb * NCB) return;                // block-uniform early exit
    const int fstart = (xcd < 3) ? xcd * 30 : 90 + (xcd - 3) * 29;
    const int fb = fstart + idx / NCB;
    const int cb = idx % NCB;

    const long t0 = (long)fb * BM;
    const int  c0 = cb * BNP;

    const int tid  = threadIdx.x;
    const int w    = tid >> 6;
    const int lane = tid & 63;
    const int l15  = lane & 15;
    const int lk   = lane >> 4;

    // Staging sources: 4 wave-loads each for A and B per K-tile (8/thread).
    const unsigned short* asrc[4];
    const unsigned short* bsrc[4];
    int ldsbase[4];
    #pragma unroll
    for (int j = 0; j < 4; ++j) {
        const int i = w * 4 + j;                 // wave-load idx 0..15
        const int c = i * 64 + lane;             // 16B-chunk idx 0..1023
        const int row = c >> 3;                  // 0..127
        const int chlog = (c & 7) ^ (row & 7);   // pre-swizzled source chunk
        ldsbase[j] = i * 512;
        long t = t0 + row; if (t > FRAMES - 1) t = FRAMES - 1;
        asrc[j] = pad + t * 512 + chlog * 8;
        int ch = c0 + (row & 63); if (ch > 512) ch = 512;
        long brow = (row < 64) ? (long)ch : (long)(513 + ch);
        bsrc[j] = bas + brow * 1024 + chlog * 8;
    }

    f32x4 acc[2][8];
    #pragma unroll
    for (int m = 0; m < 2; ++m)
        #pragma unroll
        for (int n = 0; n < 8; ++n)
            acc[m][n] = (f32x4){0.f, 0.f, 0.f, 0.f};

    // Prologue: stage K-tile 0 into buf 0.
    #pragma unroll
    for (int j = 0; j < 4; ++j) {
        __builtin_amdgcn_global_load_lds(
            (const __attribute__((address_space(1))) unsigned int*)asrc[j],
            (__attribute__((address_space(3))) unsigned int*)&lsA[0][ldsbase[j]], 16, 0, 0);
        __builtin_amdgcn_global_load_lds(
            (const __attribute__((address_space(1))) unsigned int*)bsrc[j],
            (__attribute__((address_space(3))) unsigned int*)&lsB[0][ldsbase[j]], 16, 0, 0);
    }

    for (int t = 0; t < NKT; ++t) {
        const int cur = t & 1;
        if (t + 1 < NKT) {
            const int koff = (t + 1) * BK;
            #pragma unroll
            for (int j = 0; j < 4; ++j) {
                __builtin_amdgcn_global_load_lds(
                    (const __attribute__((address_space(1))) unsigned int*)(asrc[j] + koff),
                    (__attribute__((address_space(3))) unsigned int*)&lsA[cur ^ 1][ldsbase[j]], 16, 0, 0);
                __builtin_amdgcn_global_load_lds(
                    (const __attribute__((address_space(1))) unsigned int*)(bsrc[j] + koff),
                    (__attribute__((address_space(3))) unsigned int*)&lsB[cur ^ 1][ldsbase[j]], 16, 0, 0);
            }
            asm volatile("s_waitcnt vmcnt(8)" ::: "memory");  // tile t landed; t+1 in flight
        } else {
            asm volatile("s_waitcnt vmcnt(0)" ::: "memory");
        }
        __builtin_amdgcn_s_barrier();
        asm volatile("" ::: "memory");

        #pragma unroll
        for (int s = 0; s < 2; ++s) {
            short8 af[2], bf[8];
            #pragma unroll
            for (int m = 0; m < 2; ++m) {
                const int r = w * 32 + m * 16 + l15;
                const int byt = (s * 64 + lk * 16) ^ ((r & 7) << 4);
                af[m] = *reinterpret_cast<const short8*>(
                    reinterpret_cast<const char*>(lsA[cur]) + r * 128 + byt);
            }
            #pragma unroll
            for (int n = 0; n < 8; ++n) {
                const int r = n * 16 + l15;
                const int byt = (s * 64 + lk * 16) ^ ((r & 7) << 4);
                bf[n] = *reinterpret_cast<const short8*>(
                    reinterpret_cast<const char*>(lsB[cur]) + r * 128 + byt);
            }
            #pragma unroll
            for (int m = 0; m < 2; ++m)
                #pragma unroll
                for (int n = 0; n < 8; ++n)
                    acc[m][n] = __builtin_amdgcn_mfma_f32_16x16x32_bf16(af[m], bf[n], acc[m][n], 0, 0, 0);
        }

        asm volatile("s_waitcnt lgkmcnt(0)" ::: "memory");  // all LDS reads retired
        __builtin_amdgcn_s_barrier();                       // before buf[cur] overwrite at t+2
    }

    // Epilogue: out[ch][t] = re^2 + im^2
    const int tbase = (int)t0 + w * 32;
    #pragma unroll
    for (int m = 0; m < 2; ++m) {
        #pragma unroll
        for (int n = 0; n < 4; ++n) {
            const int ch = c0 + n * 16 + l15;
            if (ch >= CHP) continue;
            const long obase = (long)ch * FRAMES;
            #pragma unroll
            for (int r = 0; r < 4; ++r) {
                const int t = tbase + m * 16 + lk * 4 + r;
                if (t < FRAMES) {
                    const float re = acc[m][n][r], im = acc[m][n + 4][r];
                    out[obase + t] = re * re + im * im;
                }
            }
        }
    }
}

extern "C" void kernel_launch(void* const* d_in, const int* in_sizes, int n_in,
                              void* d_out, int out_size, void* d_ws, size_t ws_size,
                              hipStream_t stream) {
    const float* audio = (const float*)d_in[0];
    const float* basis = (const float*)d_in[1];
    float* out = (float*)d_out;

    unsigned short* pad = (unsigned short*)d_ws;
    unsigned short* bas = pad + PADLEN;

    prep_pad_k<<<PADLEN / 4 / 256, 256, 0, stream>>>(audio, pad);
    prep_bas_k<<<NBAS / 4 / 256, 256, 0, stream>>>(basis, bas);

    stft_gemm<<<8 * 270, 256, 0, stream>>>(pad, bas, out);  // 2160 blocks, 45 idle
}

// Round 4
// 111.319 us; speedup vs baseline: 5.2439x; 1.1368x over previous
//
#include <hip/hip_runtime.h>

#define L_AUDIO 15360000
#define PADLEN  15361024   // L + 1024
#define FRAMES  30001
#define CHP     513        // channel pairs (real k, imag k+513)
#define NBAS    (1026*1024)

#define BM  256            // frames per block
#define BNP 128            // channel pairs per block (256 basis rows)
#define BK  64
#define NKT 16             // 1024 / BK
#define NCB 5              // ceil(513/128)
#define NFB 118            // ceil(30001/256)
#define NWG (NFB*NCB)      // 590

typedef __attribute__((ext_vector_type(8))) short short8;
typedef __attribute__((ext_vector_type(4))) float f32x4;

__device__ __forceinline__ unsigned short f2bf(float f) {
    unsigned int u = __float_as_uint(f);
    u += 0x7fffu + ((u >> 16) & 1u);   // round-to-nearest-even
    return (unsigned short)(u >> 16);
}

__global__ __launch_bounds__(256) void prep_pad_k(const float* __restrict__ a,
                                                  unsigned short* __restrict__ pad) {
    long i = (long)blockIdx.x * blockDim.x + threadIdx.x;   // [0, PADLEN/4)
    long p0 = i * 4;
    if (p0 >= 512 && p0 + 4 <= 512 + L_AUDIO) {
        const float4 v = *reinterpret_cast<const float4*>(a + (p0 - 512));
        ushort4 o;
        o.x = f2bf(v.x); o.y = f2bf(v.y); o.z = f2bf(v.z); o.w = f2bf(v.w);
        *reinterpret_cast<ushort4*>(pad + p0) = o;
    } else {
        for (int j = 0; j < 4; ++j) {
            long p = p0 + j;
            long src = p - 512;
            if (p < 512) src = 512 - p;
            else if (src >= L_AUDIO) src = 2L*L_AUDIO - 2 - src;
            pad[p] = f2bf(a[src]);
        }
    }
}

__global__ __launch_bounds__(256) void prep_bas_k(const float* __restrict__ b,
                                                  unsigned short* __restrict__ o) {
    long i = (long)blockIdx.x * blockDim.x + threadIdx.x;
    const float4 v = *reinterpret_cast<const float4*>(b + i * 4);
    ushort4 u;
    u.x = f2bf(v.x); u.y = f2bf(v.y); u.z = f2bf(v.z); u.w = f2bf(v.w);
    *reinterpret_cast<ushort4*>(o + i * 4) = u;
}

// 256(frames) x 256(basis rows = 128 pairs) x K=64 tiles, 8 waves (2M x 4N),
// per-wave 128x64. B-tile rows reordered in 16-row frags: frag g -> pair block
// (g>>1)*16, g&1 selects real/imag, so each wave's 4 n-frags are
// {real,imag,real,imag} of its 32 pairs and the power epilogue is wave-local.
// LDS XOR-swizzle (rule 21): linear gload_lds dest + pre-swizzled source +
// swizzled ds_read. 4 phases per K-tile, 1 half-tile prefetch issued per
// phase into the opposite buffer, counted vmcnt(2) once per tile (T4),
// setprio around MFMA clusters (T5).
__global__ __launch_bounds__(512, 2) void stft_gemm(const unsigned short* __restrict__ pad,
                                                    const unsigned short* __restrict__ bas,
                                                    float* __restrict__ out) {
    __shared__ unsigned short lsA[2][BM * BK];   // 2 x 32 KB
    __shared__ unsigned short lsB[2][BM * BK];   // 2 x 32 KB

    const int tid  = threadIdx.x;
    const int w    = tid >> 6;
    const int lane = tid & 63;
    const int l15  = lane & 15;
    const int lk   = lane >> 4;
    const int wm   = w >> 2;          // 0..1 (M half)
    const int wn   = w & 3;           // 0..3 (N quarter)

    // bijective XCD-chunked remap (m204): NWG=590 = 8*73+6
    const int orig = blockIdx.x;
    const int xcd  = orig & 7;
    const int lid  = orig >> 3;
    const int wg   = (xcd < 6 ? xcd * 74 : 6 * 74 + (xcd - 6) * 73) + lid;
    const int fb   = wg / NCB;
    const int cb   = wg - fb * NCB;
    const long t0  = (long)fb * BM;
    const int  c0  = cb * BNP;

    // Per-thread staging sources (chunk c = j*512 + tid of 2048 16B-chunks).
    const unsigned short* aS[4];
    const unsigned short* bS[4];
    #pragma unroll
    for (int j = 0; j < 4; ++j) {
        const int c   = j * 512 + tid;
        const int row = c >> 3;                  // 0..255
        const int sc  = (c & 7) ^ (row & 7);     // pre-swizzled source chunk
        long tf = t0 + row; if (tf > FRAMES - 1) tf = FRAMES - 1;
        aS[j] = pad + tf * 512 + sc * 8;
        const int g = row >> 4;                  // 16-row frag id
        int ch = c0 + (g >> 1) * 16 + (row & 15); if (ch > 512) ch = 512;
        const long brow = (g & 1) ? (long)(513 + ch) : (long)ch;
        bS[j] = bas + brow * 1024 + sc * 8;
    }

    f32x4 acc[8][4];
    #pragma unroll
    for (int a = 0; a < 8; ++a)
        #pragma unroll
        for (int b = 0; b < 4; ++b)
            acc[a][b] = (f32x4){0.f, 0.f, 0.f, 0.f};

    const int wmBase = wm * 128;
    const int wnBase = wn * 64;

#define GLD(dst, src) __builtin_amdgcn_global_load_lds( \
        (const __attribute__((address_space(1))) unsigned int*)(src), \
        (__attribute__((address_space(3))) unsigned int*)(dst), 16, 0, 0)

#define LDSREAD(basePtr, r, S) \
    (*reinterpret_cast<const short8*>(reinterpret_cast<const char*>(basePtr) \
        + (r) * 128 + ((((S) * 4 + lk) ^ ((r) & 7)) << 4)))

#define PHASE_RA(MQ, S) do { _Pragma("unroll") \
    for (int j = 0; j < 4; ++j) { \
        const int r = wmBase + ((MQ) * 4 + j) * 16 + l15; \
        af[j] = LDSREAD(curA, r, S); } } while (0)

#define PHASE_RB(S) do { _Pragma("unroll") \
    for (int b = 0; b < 4; ++b) { \
        const int r = wnBase + b * 16 + l15; \
        bf[b] = LDSREAD(curB, r, S); } } while (0)

#define PHASE_MFMA(MQ) do { \
    __builtin_amdgcn_s_setprio(1); \
    _Pragma("unroll") for (int b = 0; b < 4; ++b) \
        _Pragma("unroll") for (int j = 0; j < 4; ++j) \
            acc[(MQ)*4+j][b] = __builtin_amdgcn_mfma_f32_16x16x32_bf16( \
                af[j], bf[b], acc[(MQ)*4+j][b], 0, 0, 0); \
    __builtin_amdgcn_s_setprio(0); } while (0)

    // Prologue: stage tile 0 fully into buf 0.
    #pragma unroll
    for (int j = 0; j < 4; ++j) {
        GLD(&lsA[0][(j * 512 + tid) * 8], aS[j]);
        GLD(&lsB[0][(j * 512 + tid) * 8], bS[j]);
    }

    short8 af[4], bf[4];

    for (int t = 0; t < NKT; ++t) {
        unsigned short* curA = lsA[t & 1];
        unsigned short* curB = lsB[t & 1];
        unsigned short* nxtA = lsA[(t & 1) ^ 1];
        unsigned short* nxtB = lsB[(t & 1) ^ 1];
        const bool more = (t + 1 < NKT);
        const int ko = (t + 1) * BK;             // element offset of next tile

        // next-tile A-half0 issued BEFORE the counted wait (keeps vmcnt > 0)
        if (more) { GLD(&nxtA[(0*512+tid)*8], aS[0]+ko); GLD(&nxtA[(1*512+tid)*8], aS[1]+ko); }
        if (more) asm volatile("s_waitcnt vmcnt(2)" ::: "memory");
        else      asm volatile("s_waitcnt vmcnt(0)" ::: "memory");
        __builtin_amdgcn_s_barrier();

        // phase 1: (mq=0, s=0) + B(s=0)
        PHASE_RA(0, 0); PHASE_RB(0);
        if (more) { GLD(&nxtA[(2*512+tid)*8], aS[2]+ko); GLD(&nxtA[(3*512+tid)*8], aS[3]+ko); }
        __builtin_amdgcn_s_barrier();
        PHASE_MFMA(0);
        __builtin_amdgcn_s_barrier();

        // phase 2: (mq=1, s=0), B reused
        PHASE_RA(1, 0);
        if (more) { GLD(&nxtB[(0*512+tid)*8], bS[0]+ko); GLD(&nxtB[(1*512+tid)*8], bS[1]+ko); }
        __builtin_amdgcn_s_barrier();
        PHASE_MFMA(1);
        __builtin_amdgcn_s_barrier();

        // phase 3: (mq=0, s=1) + B(s=1)
        PHASE_RA(0, 1); PHASE_RB(1);
        if (more) { GLD(&nxtB[(2*512+tid)*8], bS[2]+ko); GLD(&nxtB[(3*512+tid)*8], bS[3]+ko); }
        __builtin_amdgcn_s_barrier();
        PHASE_MFMA(0);
        __builtin_amdgcn_s_barrier();

        // phase 4: (mq=1, s=1)
        PHASE_RA(1, 1);
        __builtin_amdgcn_s_barrier();
        PHASE_MFMA(1);
        __builtin_amdgcn_s_barrier();
    }

    // Epilogue: out[ch][t] = re^2 + im^2
    // D layout: col = lane&15 (pair), row = lk*4 + reg (frame)
    const int tb = (int)t0 + wmBase;
    #pragma unroll
    for (int a = 0; a < 8; ++a) {
        #pragma unroll
        for (int q = 0; q < 2; ++q) {
            const int ch = c0 + wn * 32 + q * 16 + l15;
            if (ch >= CHP) continue;
            const long ob = (long)ch * FRAMES;
            const int tv = tb + a * 16 + lk * 4;
            const f32x4 re = acc[a][q * 2];
            const f32x4 im = acc[a][q * 2 + 1];
            if (tv + 3 < FRAMES) {
                #pragma unroll
                for (int r = 0; r < 4; ++r)
                    out[ob + tv + r] = re[r] * re[r] + im[r] * im[r];
            } else {
                #pragma unroll
                for (int r = 0; r < 4; ++r)
                    if (tv + r < FRAMES)
                        out[ob + tv + r] = re[r] * re[r] + im[r] * im[r];
            }
        }
    }
}

extern "C" void kernel_launch(void* const* d_in, const int* in_sizes, int n_in,
                              void* d_out, int out_size, void* d_ws, size_t ws_size,
                              hipStream_t stream) {
    const float* audio = (const float*)d_in[0];
    const float* basis = (const float*)d_in[1];
    float* out = (float*)d_out;

    unsigned short* pad = (unsigned short*)d_ws;
    unsigned short* bas = pad + PADLEN;

    prep_pad_k<<<PADLEN / 4 / 256, 256, 0, stream>>>(audio, pad);
    prep_bas_k<<<NBAS / 4 / 256, 256, 0, stream>>>(basis, bas);

    stft_gemm<<<NWG, 512, 0, stream>>>(pad, bas, out);
}